// Round 6
// baseline (197.028 us; speedup 1.0000x reference)
//
#include <hip/hip_runtime.h>
#include <hip/hip_bf16.h>

typedef float f32x4 __attribute__((ext_vector_type(4)));
typedef short short8 __attribute__((ext_vector_type(8)));
typedef short short4v __attribute__((ext_vector_type(4)));

#define MFMA(a, b, c) __builtin_amdgcn_mfma_f32_16x16x32_bf16((a), (b), (c), 0, 0, 0)

#if __has_builtin(__builtin_amdgcn_exp2f)
#define EXP2(x) __builtin_amdgcn_exp2f(x)
#else
#define EXP2(x) exp2f(x)
#endif

#define B_  2
#define N_  2048
#define C_  1024
#define H_  16
#define HD_ 64
#define M_  (B_ * N_)   // 4096

// softmax scale (1/8) * log2(e), folded into Q at qkv epilogue
#define QSCALE 0.18033688011112042f

typedef const __attribute__((address_space(1))) void* gp_t;
typedef __attribute__((address_space(3))) void* sp_t;
#define GLL16(g, s) __builtin_amdgcn_global_load_lds((gp_t)(const void*)(g), (sp_t)(void*)(s), 16, 0, 0)

__device__ __forceinline__ short f2bf(float f) {
    union { float fv; unsigned u; } v; v.fv = f;
    unsigned r = v.u + 0x7fffu + ((v.u >> 16) & 1u);  // RNE
    return (short)(r >> 16);
}
__device__ __forceinline__ unsigned pack_rne(float a, float b) {
    return (unsigned)(unsigned short)f2bf(a) | ((unsigned)(unsigned short)f2bf(b) << 16);
}

// ---------------- fp32 -> bf16 conversion pass ----------------
__global__ __launch_bounds__(256) void convert_kernel(
    const float* __restrict__ x,  const float* __restrict__ wq,
    const float* __restrict__ wk, const float* __restrict__ wv,
    const float* __restrict__ wo, short* __restrict__ dst)
{
    size_t e = ((size_t)blockIdx.x * 256 + threadIdx.x) * 8;
    const float* src; size_t off;
    if (e < 4194304)      { src = x;  off = e; }
    else if (e < 5242880) { src = wq; off = e - 4194304; }
    else if (e < 6291456) { src = wk; off = e - 5242880; }
    else if (e < 7340032) { src = wv; off = e - 6291456; }
    else                  { src = wo; off = e - 7340032; }
    float4 a = *(const float4*)(src + off);
    float4 b = *(const float4*)(src + off + 4);
    short8 s;
    s[0] = f2bf(a.x); s[1] = f2bf(a.y); s[2] = f2bf(a.z); s[3] = f2bf(a.w);
    s[4] = f2bf(b.x); s[5] = f2bf(b.y); s[6] = f2bf(b.z); s[7] = f2bf(b.w);
    *(short8*)(dst + e) = s;
}

// ---------------- fused QKV GEMM (R3: BK=64 + chunk-XOR swizzle) -----------
// R6: source byte-identical to R4/R5. R5 measured this kernel at 79 us vs
// <=53.6 us in R4's build with IDENTICAL source — suspected co-compile
// regalloc perturbation (rule #19) from the added attn_full kernel; this
// round removes that dead kernel to discriminate.
__global__ __launch_bounds__(256) void qkv_gemm(
    const short* __restrict__ xb, const short* __restrict__ Wb,
    short* __restrict__ Qb, short* __restrict__ Kb, short* __restrict__ Vt)
{
    const int m0 = blockIdx.x * 128;
    const int n0 = blockIdx.y * 128;
    __shared__ short As[128 * 64];   // 16 KB
    __shared__ short Bs[128 * 64];   // 16 KB
    const int tid  = threadIdx.x;
    const int wave = tid >> 6, lane = tid & 63;
    const int quad = lane >> 4, l16 = lane & 15;
    const int wr = (wave >> 1) * 64, wc = (wave & 1) * 64;
    const int sw = l16 & 7;

    const int rS = tid >> 3;
    const int cS = (tid & 7) ^ (rS & 7);
    const short* A_src = xb + (size_t)(m0 + rS) * C_ + cS * 8;
    const short* B_src = Wb + (size_t)(n0 + rS) * C_ + cS * 8;

    f32x4 acc[4][4] = {};

    for (int kk = 0; kk < C_; kk += 64) {
        __syncthreads();
        #pragma unroll
        for (int it = 0; it < 4; ++it) {
            GLL16(A_src + (size_t)(it * 32) * C_ + kk, &As[it * 2048 + tid * 8]);
            GLL16(B_src + (size_t)(it * 32) * C_ + kk, &Bs[it * 2048 + tid * 8]);
        }
        __syncthreads();
        short8 af[4][2], bf[4][2];
        #pragma unroll
        for (int mi = 0; mi < 4; ++mi) {
            int row = (wr + mi * 16 + l16) * 64;
            af[mi][0] = *(const short8*)&As[row + ((quad    ) ^ sw) * 8];
            af[mi][1] = *(const short8*)&As[row + ((quad + 4) ^ sw) * 8];
        }
        #pragma unroll
        for (int ni = 0; ni < 4; ++ni) {
            int row = (wc + ni * 16 + l16) * 64;
            bf[ni][0] = *(const short8*)&Bs[row + ((quad    ) ^ sw) * 8];
            bf[ni][1] = *(const short8*)&Bs[row + ((quad + 4) ^ sw) * 8];
        }
        #pragma unroll
        for (int k2 = 0; k2 < 2; ++k2)
        #pragma unroll
        for (int mi = 0; mi < 4; ++mi)
        #pragma unroll
        for (int ni = 0; ni < 4; ++ni)
            acc[mi][ni] = MFMA(af[mi][k2], bf[ni][k2], acc[mi][ni]);
    }

    const int which = n0 >> 10;        // block-uniform: 0=Q 1=K 2=V
    const int nb = n0 & 1023;
    #pragma unroll
    for (int mi = 0; mi < 4; ++mi)
    #pragma unroll
    for (int ni = 0; ni < 4; ++ni)
    #pragma unroll
    for (int r = 0; r < 4; ++r) {
        int m  = m0 + wr + mi * 16 + quad * 4 + r;
        int cc = nb + wc + ni * 16 + l16;
        float av = acc[mi][ni][r];
        if (which == 0) av *= QSCALE;
        short bv = f2bf(av);
        int bb = m >> 11, ns = m & (N_ - 1);
        int h = cc >> 6, d = cc & 63;
        size_t bh = (size_t)(bb * H_ + h);
        if (which == 0)      Qb[(bh * N_ + ns) * HD_ + d] = bv;
        else if (which == 1) Kb[(bh * N_ + ns) * HD_ + d] = bv;
        else                 Vt[(bh * HD_ + d) * N_ + ns] = bv;  // V transposed
    }
}

// ---------------- Flash attention, split-j x2 (R5, kept) --------------------
__global__ __launch_bounds__(256, 5) void attn_split(
    const short* __restrict__ Qb, const short* __restrict__ Kb,
    const short* __restrict__ Vt, float* __restrict__ Opart,
    float* __restrict__ lpart)
{
    // 2048 blocks; XCD-chunk (2048 % 8 == 0): 256 per XCD -> 4 bh per XCD.
    const int bid = blockIdx.x;
    const int swz = (bid & 7) * 256 + (bid >> 3);
    const int bh = swz >> 6;
    const int i0 = ((swz >> 1) & 31) * 64;
    const int sp = swz & 1;             // j-split: sp*1024 .. sp*1024+1023
    __shared__ short Ks[2][64 * 64];    // 16 KB
    __shared__ short Vs[2][64 * 64];    // 16 KB, Vs[d][j]
    const int tid  = threadIdx.x;
    const int wave = tid >> 6, lane = tid & 63;
    const int quad = lane >> 4, l16 = lane & 15;
    const int sw = l16 & 7;             // frag-read swizzle key (row&7 == l16&7)

    const short* Qg = Qb + ((size_t)bh * N_ + i0) * HD_;
    const short* Kg = Kb + (size_t)bh * N_ * HD_;
    const short* Vg = Vt + (size_t)bh * HD_ * N_;

    const int row0 = tid >> 3,  c0 = (tid & 7) ^ (row0 & 7);
    const int row1 = row0 + 32, c1 = (tid & 7) ^ (row1 & 7);
    const short* KgA0 = Kg + (sp * 1024 + row0) * HD_ + c0 * 8;
    const short* KgA1 = Kg + (sp * 1024 + row1) * HD_ + c1 * 8;
    const short* VgA0 = Vg + (size_t)row0 * N_ + sp * 1024 + c0 * 8;
    const short* VgA1 = Vg + (size_t)row1 * N_ + sp * 1024 + c1 * 8;

    // Q fragments: global -> reg (read once; no LDS round-trip)
    short8 qf[2];
    {
        const short* qrow = Qg + (wave * 16 + l16) * HD_;
        qf[0] = *(const short8*)(qrow + quad * 8);
        qf[1] = *(const short8*)(qrow + quad * 8 + 32);
    }

    GLL16(KgA0, &Ks[0][tid * 8]);
    GLL16(KgA1, &Ks[0][(tid + 256) * 8]);
    GLL16(VgA0, &Vs[0][tid * 8]);
    GLL16(VgA1, &Vs[0][(tid + 256) * 8]);
    __syncthreads();

    f32x4 o[4] = {};
    float lrow = 0.f;

    for (int jt = 0; jt < 16; ++jt) {
        const int cur = jt & 1;
        if (jt + 1 < 16) {
            int j1 = (jt + 1) * 64;
            GLL16(KgA0 + (size_t)j1 * HD_, &Ks[cur ^ 1][tid * 8]);
            GLL16(KgA1 + (size_t)j1 * HD_, &Ks[cur ^ 1][(tid + 256) * 8]);
            GLL16(VgA0 + j1, &Vs[cur ^ 1][tid * 8]);
            GLL16(VgA1 + j1, &Vs[cur ^ 1][(tid + 256) * 8]);
        }
        const short* Kc = Ks[cur];
        const short* Vc = Vs[cur];

        #pragma unroll
        for (int half = 0; half < 2; ++half) {
            unsigned pq[4];
            #pragma unroll
            for (int nio = 0; nio < 2; ++nio) {
                int ni = half * 2 + nio;
                int krow = (ni * 16 + l16) * 64;
                short8 kf0 = *(const short8*)&Kc[krow + ((quad ^ sw) * 8)];
                short8 kf1 = *(const short8*)&Kc[krow + (((quad + 4) ^ sw) * 8)];
                f32x4 st = {0.f, 0.f, 0.f, 0.f};
                __builtin_amdgcn_s_setprio(1);
                st = MFMA(kf0, qf[0], st);
                st = MFMA(kf1, qf[1], st);   // S^T[j=16ni+4q+r][i=l16]
                __builtin_amdgcn_s_setprio(0);
                union { float f; unsigned u; } e0, e1, e2, e3;
                e0.f = EXP2(st[0]); e1.f = EXP2(st[1]);
                e2.f = EXP2(st[2]); e3.f = EXP2(st[3]);
                lrow += (e0.f + e1.f) + (e2.f + e3.f);
                pq[nio * 2]     = __builtin_amdgcn_perm(e1.u, e0.u, 0x07060302u);
                pq[nio * 2 + 1] = __builtin_amdgcn_perm(e3.u, e2.u, 0x07060302u);
            }
            #pragma unroll
            for (int di = 0; di < 4; ++di) {
                int vrow = (di * 16 + l16) * 64;
                int ch1 = (half * 4 +     (quad >> 1)) ^ sw;
                int ch2 = (half * 4 + 2 + (quad >> 1)) ^ sw;
                union { struct { short4v lo, hi; } p; short8 v; } va;
                va.p.lo = *(const short4v*)&Vc[vrow + ch1 * 8 + (quad & 1) * 4];
                va.p.hi = *(const short4v*)&Vc[vrow + ch2 * 8 + (quad & 1) * 4];
                union { unsigned u[4]; short8 v; } pb;
                pb.u[0] = pq[0]; pb.u[1] = pq[1];
                pb.u[2] = pq[2]; pb.u[3] = pq[3];
                __builtin_amdgcn_s_setprio(1);
                o[di] = MFMA(va.v, pb.v, o[di]);
                __builtin_amdgcn_s_setprio(0);
            }
        }
        __syncthreads();
    }

    {
        float l = lrow;
        l += __shfl_xor(l, 16, 64);
        l += __shfl_xor(l, 32, 64);
        int ig = i0 + wave * 16 + l16;
        float* obase = Opart + ((size_t)(sp * 32 + bh) * N_ + ig) * HD_;
        #pragma unroll
        for (int di = 0; di < 4; ++di)   // d = di*16 + quad*4 + r, unnormalized
            *(f32x4*)(obase + di * 16 + quad * 4) = o[di];
        if (quad == 0) lpart[sp * 65536 + bh * N_ + ig] = l;
    }
}

// merge: O = (O0 + O1) / (l0 + l1), scatter to head-interleaved bf16 layout
__global__ __launch_bounds__(256) void merge_kernel(
    const float* __restrict__ Opart, const float* __restrict__ lpart,
    short* __restrict__ Ob)
{
    int e8 = (blockIdx.x * 256 + threadIdx.x) * 8;   // [bh][ig][d] linear
    int bh = e8 >> 17;
    int rem = e8 & 131071;
    int ig = rem >> 6, d = rem & 63;
    f32x4 a0 = *(const f32x4*)(Opart + e8);
    f32x4 a1 = *(const f32x4*)(Opart + e8 + 4);
    f32x4 b0 = *(const f32x4*)(Opart + 4194304 + e8);
    f32x4 b1 = *(const f32x4*)(Opart + 4194304 + e8 + 4);
    float inv = 1.f / (lpart[bh * N_ + ig] + lpart[65536 + bh * N_ + ig]);
    short8 s;
    s[0] = f2bf((a0[0] + b0[0]) * inv); s[1] = f2bf((a0[1] + b0[1]) * inv);
    s[2] = f2bf((a0[2] + b0[2]) * inv); s[3] = f2bf((a0[3] + b0[3]) * inv);
    s[4] = f2bf((a1[0] + b1[0]) * inv); s[5] = f2bf((a1[1] + b1[1]) * inv);
    s[6] = f2bf((a1[2] + b1[2]) * inv); s[7] = f2bf((a1[3] + b1[3]) * inv);
    int b = bh >> 4, h = bh & (H_ - 1);
    *(short8*)&Ob[((size_t)(b * N_ + ig)) * C_ + h * HD_ + d] = s;
}

// ---------------- Output projection (R4: BK=64 + chunk-XOR swizzle) --------
__global__ __launch_bounds__(256) void proj_gemm(
    const short* __restrict__ Ob, const short* __restrict__ wob,
    const float* __restrict__ bo, float* __restrict__ out)
{
    const int m0 = blockIdx.x * 64;
    const int n0 = blockIdx.y * 128;
    __shared__ short As[64 * 64];    // 8 KB
    __shared__ short Bs[128 * 64];   // 16 KB
    const int tid  = threadIdx.x;
    const int wave = tid >> 6, lane = tid & 63;
    const int quad = lane >> 4, l16 = lane & 15;
    const int wr = (wave >> 1) * 32, wc = (wave & 1) * 64;
    const int sw = l16 & 7;

    const int rS = tid >> 3;
    const int cS = (tid & 7) ^ (rS & 7);
    const short* A_src = Ob  + (size_t)(m0 + rS) * C_ + cS * 8;
    const short* B_src = wob + (size_t)(n0 + rS) * C_ + cS * 8;

    f32x4 acc[2][4] = {};

    for (int kk = 0; kk < C_; kk += 64) {
        __syncthreads();
        GLL16(A_src + kk, &As[tid * 8]);
        GLL16(A_src + (size_t)32 * C_ + kk, &As[(tid + 256) * 8]);
        #pragma unroll
        for (int it = 0; it < 4; ++it)
            GLL16(B_src + (size_t)(it * 32) * C_ + kk, &Bs[it * 2048 + tid * 8]);
        __syncthreads();
        short8 af[2][2], bf[4][2];
        #pragma unroll
        for (int mi = 0; mi < 2; ++mi) {
            int row = (wr + mi * 16 + l16) * 64;
            af[mi][0] = *(const short8*)&As[row + ((quad    ) ^ sw) * 8];
            af[mi][1] = *(const short8*)&As[row + ((quad + 4) ^ sw) * 8];
        }
        #pragma unroll
        for (int ni = 0; ni < 4; ++ni) {
            int row = (wc + ni * 16 + l16) * 64;
            bf[ni][0] = *(const short8*)&Bs[row + ((quad    ) ^ sw) * 8];
            bf[ni][1] = *(const short8*)&Bs[row + ((quad + 4) ^ sw) * 8];
        }
        #pragma unroll
        for (int k2 = 0; k2 < 2; ++k2)
        #pragma unroll
        for (int mi = 0; mi < 2; ++mi)
        #pragma unroll
        for (int ni = 0; ni < 4; ++ni)
            acc[mi][ni] = MFMA(af[mi][k2], bf[ni][k2], acc[mi][ni]);
    }

    #pragma unroll
    for (int mi = 0; mi < 2; ++mi)
    #pragma unroll
    for (int ni = 0; ni < 4; ++ni)
    #pragma unroll
    for (int r = 0; r < 4; ++r) {
        int m = m0 + wr + mi * 16 + quad * 4 + r;
        int c = n0 + wc + ni * 16 + l16;
        out[(size_t)m * C_ + c] = acc[mi][ni][r] + bo[c];
    }
}

extern "C" void kernel_launch(void* const* d_in, const int* in_sizes, int n_in,
                              void* d_out, int out_size, void* d_ws, size_t ws_size,
                              hipStream_t stream) {
    const float* x  = (const float*)d_in[0];
    const float* wq = (const float*)d_in[1];
    const float* wk = (const float*)d_in[2];
    const float* wv = (const float*)d_in[3];
    const float* wo = (const float*)d_in[4];
    const float* bo = (const float*)d_in[5];
    float* out = (float*)d_out;

    short* xb  = (short*)d_ws;        // 4M shorts
    short* Wb  = xb  + 4194304;       // 3M (wq|wk|wv)
    short* wob = Wb  + 3145728;       // 1M
    short* Qb  = wob + 1048576;       // 4M
    short* Kb  = Qb  + 4194304;       // 4M
    short* Vt  = Kb  + 4194304;       // 4M
    short* Obuf= Vt  + 4194304;       // 4M
    float* Opart = (float*)(Obuf + 4194304);  // 2 x 4.19M f32 (split partials)
    float* lpart = Opart + 2 * 4194304;       // 2 x 65536 f32

    dim3 blk(256);
    convert_kernel<<<4096, blk, 0, stream>>>(x, wq, wk, wv, wo, xb);
    qkv_gemm<<<dim3(M_ / 128, 3072 / 128), blk, 0, stream>>>(xb, Wb, Qb, Kb, Vt);
    attn_split<<<2048, blk, 0, stream>>>(Qb, Kb, Vt, Opart, lpart);
    merge_kernel<<<2048, blk, 0, stream>>>(Opart, lpart, Obuf);
    proj_gemm<<<dim3(M_ / 64, C_ / 128), blk, 0, stream>>>(Obuf, wob, bo, out);
}

// Round 7
// 190.709 us; speedup vs baseline: 1.0331x; 1.0331x over previous
//
#include <hip/hip_runtime.h>
#include <hip/hip_bf16.h>

typedef float f32x4 __attribute__((ext_vector_type(4)));
typedef short short8 __attribute__((ext_vector_type(8)));
typedef short short4v __attribute__((ext_vector_type(4)));

#define MFMA(a, b, c) __builtin_amdgcn_mfma_f32_16x16x32_bf16((a), (b), (c), 0, 0, 0)

#if __has_builtin(__builtin_amdgcn_exp2f)
#define EXP2(x) __builtin_amdgcn_exp2f(x)
#else
#define EXP2(x) exp2f(x)
#endif

#define B_  2
#define N_  2048
#define C_  1024
#define H_  16
#define HD_ 64
#define M_  (B_ * N_)   // 4096

// softmax scale (1/8) * log2(e), folded into Q at qkv epilogue
#define QSCALE 0.18033688011112042f

typedef const __attribute__((address_space(1))) void* gp_t;
typedef __attribute__((address_space(3))) void* sp_t;
#define GLL16(g, s) __builtin_amdgcn_global_load_lds((gp_t)(const void*)(g), (sp_t)(void*)(s), 16, 0, 0)

__device__ __forceinline__ short f2bf(float f) {
    union { float fv; unsigned u; } v; v.fv = f;
    unsigned r = v.u + 0x7fffu + ((v.u >> 16) & 1u);  // RNE
    return (short)(r >> 16);
}
__device__ __forceinline__ unsigned pack_rne(float a, float b) {
    return (unsigned)(unsigned short)f2bf(a) | ((unsigned)(unsigned short)f2bf(b) << 16);
}

// ---------------- fp32 -> bf16 conversion pass ----------------
__global__ __launch_bounds__(256) void convert_kernel(
    const float* __restrict__ x,  const float* __restrict__ wq,
    const float* __restrict__ wk, const float* __restrict__ wv,
    const float* __restrict__ wo, short* __restrict__ dst)
{
    size_t e = ((size_t)blockIdx.x * 256 + threadIdx.x) * 8;
    const float* src; size_t off;
    if (e < 4194304)      { src = x;  off = e; }
    else if (e < 5242880) { src = wq; off = e - 4194304; }
    else if (e < 6291456) { src = wk; off = e - 5242880; }
    else if (e < 7340032) { src = wv; off = e - 6291456; }
    else                  { src = wo; off = e - 7340032; }
    float4 a = *(const float4*)(src + off);
    float4 b = *(const float4*)(src + off + 4);
    short8 s;
    s[0] = f2bf(a.x); s[1] = f2bf(a.y); s[2] = f2bf(a.z); s[3] = f2bf(a.w);
    s[4] = f2bf(b.x); s[5] = f2bf(b.y); s[6] = f2bf(b.z); s[7] = f2bf(b.w);
    *(short8*)(dst + e) = s;
}

// ---------------- fused QKV GEMM (R3: BK=64 + chunk-XOR swizzle) -----------
__global__ __launch_bounds__(256) void qkv_gemm(
    const short* __restrict__ xb, const short* __restrict__ Wb,
    short* __restrict__ Qb, short* __restrict__ Kb, short* __restrict__ Vt)
{
    const int m0 = blockIdx.x * 128;
    const int n0 = blockIdx.y * 128;
    __shared__ short As[128 * 64];   // 16 KB
    __shared__ short Bs[128 * 64];   // 16 KB
    const int tid  = threadIdx.x;
    const int wave = tid >> 6, lane = tid & 63;
    const int quad = lane >> 4, l16 = lane & 15;
    const int wr = (wave >> 1) * 64, wc = (wave & 1) * 64;
    const int sw = l16 & 7;

    const int rS = tid >> 3;
    const int cS = (tid & 7) ^ (rS & 7);
    const short* A_src = xb + (size_t)(m0 + rS) * C_ + cS * 8;
    const short* B_src = Wb + (size_t)(n0 + rS) * C_ + cS * 8;

    f32x4 acc[4][4] = {};

    for (int kk = 0; kk < C_; kk += 64) {
        __syncthreads();
        #pragma unroll
        for (int it = 0; it < 4; ++it) {
            GLL16(A_src + (size_t)(it * 32) * C_ + kk, &As[it * 2048 + tid * 8]);
            GLL16(B_src + (size_t)(it * 32) * C_ + kk, &Bs[it * 2048 + tid * 8]);
        }
        __syncthreads();
        short8 af[4][2], bf[4][2];
        #pragma unroll
        for (int mi = 0; mi < 4; ++mi) {
            int row = (wr + mi * 16 + l16) * 64;
            af[mi][0] = *(const short8*)&As[row + ((quad    ) ^ sw) * 8];
            af[mi][1] = *(const short8*)&As[row + ((quad + 4) ^ sw) * 8];
        }
        #pragma unroll
        for (int ni = 0; ni < 4; ++ni) {
            int row = (wc + ni * 16 + l16) * 64;
            bf[ni][0] = *(const short8*)&Bs[row + ((quad    ) ^ sw) * 8];
            bf[ni][1] = *(const short8*)&Bs[row + ((quad + 4) ^ sw) * 8];
        }
        #pragma unroll
        for (int k2 = 0; k2 < 2; ++k2)
        #pragma unroll
        for (int mi = 0; mi < 4; ++mi)
        #pragma unroll
        for (int ni = 0; ni < 4; ++ni)
            acc[mi][ni] = MFMA(af[mi][k2], bf[ni][k2], acc[mi][ni]);
    }

    const int which = n0 >> 10;        // block-uniform: 0=Q 1=K 2=V
    const int nb = n0 & 1023;
    #pragma unroll
    for (int mi = 0; mi < 4; ++mi)
    #pragma unroll
    for (int ni = 0; ni < 4; ++ni)
    #pragma unroll
    for (int r = 0; r < 4; ++r) {
        int m  = m0 + wr + mi * 16 + quad * 4 + r;
        int cc = nb + wc + ni * 16 + l16;
        float av = acc[mi][ni][r];
        if (which == 0) av *= QSCALE;
        short bv = f2bf(av);
        int bb = m >> 11, ns = m & (N_ - 1);
        int h = cc >> 6, d = cc & 63;
        size_t bh = (size_t)(bb * H_ + h);
        if (which == 0)      Qb[(bh * N_ + ns) * HD_ + d] = bv;
        else if (which == 1) Kb[(bh * N_ + ns) * HD_ + d] = bv;
        else                 Vt[(bh * HD_ + d) * N_ + ns] = bv;  // V transposed
    }
}

// ---------------- Flash attention, split-j x2, 2-strip ----------------------
// R7: R6 counters proved LDS-BW-bound: 96 KB LDS traffic per 64-row block-jt
// = 58 TB/s (84% of 69 TB/s ceiling) in BOTH R4 and R6 — which is why
// split-j alone was null. Fix: 2 strips/wave (128 Q-rows/block) so the K/V
// fragment reads (whole tile per wave) amortize over 2x MFMA work -> LDS
// traffic/work halved (1.57 GB total). Split-j kept so grid = 1024 = 4/CU.
__global__ __launch_bounds__(256, 4) void attn_split(
    const short* __restrict__ Qb, const short* __restrict__ Kb,
    const short* __restrict__ Vt, float* __restrict__ Opart,
    float* __restrict__ lpart)
{
    // 1024 blocks; XCD-chunk (1024 % 8 == 0): 128 per XCD -> 4 bh per XCD.
    const int bid = blockIdx.x;
    const int swz = (bid & 7) * 128 + (bid >> 3);
    const int bh = swz >> 5;                 // 32
    const int i0 = ((swz >> 1) & 15) * 128;  // 16 i-tiles of 128 rows
    const int sp = swz & 1;                  // j-split: sp*1024 ..
    __shared__ short Ks[2][64 * 64];    // 16 KB
    __shared__ short Vs[2][64 * 64];    // 16 KB, Vs[d][j]
    const int tid  = threadIdx.x;
    const int wave = tid >> 6, lane = tid & 63;
    const int quad = lane >> 4, l16 = lane & 15;
    const int sw = l16 & 7;             // frag-read swizzle key (row&7 == l16&7)

    const short* Qg = Qb + ((size_t)bh * N_ + i0) * HD_;
    const short* Kg = Kb + (size_t)bh * N_ * HD_;
    const short* Vg = Vt + (size_t)bh * HD_ * N_;

    const int row0 = tid >> 3,  c0 = (tid & 7) ^ (row0 & 7);
    const int row1 = row0 + 32, c1 = (tid & 7) ^ (row1 & 7);
    const short* KgA0 = Kg + (sp * 1024 + row0) * HD_ + c0 * 8;
    const short* KgA1 = Kg + (sp * 1024 + row1) * HD_ + c1 * 8;
    const short* VgA0 = Vg + (size_t)row0 * N_ + sp * 1024 + c0 * 8;
    const short* VgA1 = Vg + (size_t)row1 * N_ + sp * 1024 + c1 * 8;

    // Q fragments: global -> reg (read once; no LDS round-trip); 2 strips.
    short8 qf[2][2];
    #pragma unroll
    for (int s = 0; s < 2; ++s) {
        const short* qrow = Qg + (wave * 32 + s * 16 + l16) * HD_;
        qf[s][0] = *(const short8*)(qrow + quad * 8);
        qf[s][1] = *(const short8*)(qrow + quad * 8 + 32);
    }

    GLL16(KgA0, &Ks[0][tid * 8]);
    GLL16(KgA1, &Ks[0][(tid + 256) * 8]);
    GLL16(VgA0, &Vs[0][tid * 8]);
    GLL16(VgA1, &Vs[0][(tid + 256) * 8]);
    __syncthreads();

    f32x4 o[2][4] = {};
    float lrow[2] = {0.f, 0.f};

    for (int jt = 0; jt < 16; ++jt) {
        const int cur = jt & 1;
        if (jt + 1 < 16) {
            int j1 = (jt + 1) * 64;
            GLL16(KgA0 + (size_t)j1 * HD_, &Ks[cur ^ 1][tid * 8]);
            GLL16(KgA1 + (size_t)j1 * HD_, &Ks[cur ^ 1][(tid + 256) * 8]);
            GLL16(VgA0 + j1, &Vs[cur ^ 1][tid * 8]);
            GLL16(VgA1 + j1, &Vs[cur ^ 1][(tid + 256) * 8]);
        }
        const short* Kc = Ks[cur];
        const short* Vc = Vs[cur];

        #pragma unroll
        for (int half = 0; half < 2; ++half) {
            // S^T for ni = 2*half, 2*half+1; K frags read once, used by both
            // strips. P stays in registers as the permuted PV B-fragment.
            unsigned pq[2][4];
            #pragma unroll
            for (int nio = 0; nio < 2; ++nio) {
                int ni = half * 2 + nio;
                int krow = (ni * 16 + l16) * 64;
                short8 kf0 = *(const short8*)&Kc[krow + ((quad ^ sw) * 8)];
                short8 kf1 = *(const short8*)&Kc[krow + (((quad + 4) ^ sw) * 8)];
                #pragma unroll
                for (int s = 0; s < 2; ++s) {
                    f32x4 st = {0.f, 0.f, 0.f, 0.f};
                    __builtin_amdgcn_s_setprio(1);
                    st = MFMA(kf0, qf[s][0], st);
                    st = MFMA(kf1, qf[s][1], st);   // S^T[j=16ni+4q+r][i=strip+l16]
                    __builtin_amdgcn_s_setprio(0);
                    union { float f; unsigned u; } e0, e1, e2, e3;
                    e0.f = EXP2(st[0]); e1.f = EXP2(st[1]);
                    e2.f = EXP2(st[2]); e3.f = EXP2(st[3]);
                    lrow[s] += (e0.f + e1.f) + (e2.f + e3.f);
                    pq[s][nio * 2]     = __builtin_amdgcn_perm(e1.u, e0.u, 0x07060302u);
                    pq[s][nio * 2 + 1] = __builtin_amdgcn_perm(e3.u, e2.u, 0x07060302u);
                }
            }
            // PV: V frags read once per di, shared across strips.
            #pragma unroll
            for (int di = 0; di < 4; ++di) {
                int vrow = (di * 16 + l16) * 64;
                int ch1 = (half * 4 +     (quad >> 1)) ^ sw;
                int ch2 = (half * 4 + 2 + (quad >> 1)) ^ sw;
                union { struct { short4v lo, hi; } p; short8 v; } va;
                va.p.lo = *(const short4v*)&Vc[vrow + ch1 * 8 + (quad & 1) * 4];
                va.p.hi = *(const short4v*)&Vc[vrow + ch2 * 8 + (quad & 1) * 4];
                __builtin_amdgcn_s_setprio(1);
                #pragma unroll
                for (int s = 0; s < 2; ++s) {
                    union { unsigned u[4]; short8 v; } pb;
                    pb.u[0] = pq[s][0]; pb.u[1] = pq[s][1];
                    pb.u[2] = pq[s][2]; pb.u[3] = pq[s][3];
                    o[s][di] = MFMA(va.v, pb.v, o[s][di]);
                }
                __builtin_amdgcn_s_setprio(0);
            }
        }
        __syncthreads();
    }

    #pragma unroll
    for (int s = 0; s < 2; ++s) {
        float l = lrow[s];
        l += __shfl_xor(l, 16, 64);
        l += __shfl_xor(l, 32, 64);
        int ig = i0 + wave * 32 + s * 16 + l16;
        float* obase = Opart + ((size_t)(sp * 32 + bh) * N_ + ig) * HD_;
        #pragma unroll
        for (int di = 0; di < 4; ++di)   // d = di*16 + quad*4 + r, unnormalized
            *(f32x4*)(obase + di * 16 + quad * 4) = o[s][di];
        if (quad == 0) lpart[sp * 65536 + bh * N_ + ig] = l;
    }
}

// merge: O = (O0 + O1) / (l0 + l1), scatter to head-interleaved bf16 layout
__global__ __launch_bounds__(256) void merge_kernel(
    const float* __restrict__ Opart, const float* __restrict__ lpart,
    short* __restrict__ Ob)
{
    int e8 = (blockIdx.x * 256 + threadIdx.x) * 8;   // [bh][ig][d] linear
    int bh = e8 >> 17;
    int rem = e8 & 131071;
    int ig = rem >> 6, d = rem & 63;
    f32x4 a0 = *(const f32x4*)(Opart + e8);
    f32x4 a1 = *(const f32x4*)(Opart + e8 + 4);
    f32x4 b0 = *(const f32x4*)(Opart + 4194304 + e8);
    f32x4 b1 = *(const f32x4*)(Opart + 4194304 + e8 + 4);
    float inv = 1.f / (lpart[bh * N_ + ig] + lpart[65536 + bh * N_ + ig]);
    short8 s;
    s[0] = f2bf((a0[0] + b0[0]) * inv); s[1] = f2bf((a0[1] + b0[1]) * inv);
    s[2] = f2bf((a0[2] + b0[2]) * inv); s[3] = f2bf((a0[3] + b0[3]) * inv);
    s[4] = f2bf((a1[0] + b1[0]) * inv); s[5] = f2bf((a1[1] + b1[1]) * inv);
    s[6] = f2bf((a1[2] + b1[2]) * inv); s[7] = f2bf((a1[3] + b1[3]) * inv);
    int b = bh >> 4, h = bh & (H_ - 1);
    *(short8*)&Ob[((size_t)(b * N_ + ig)) * C_ + h * HD_ + d] = s;
}

// ---------------- Output projection (R4: BK=64 + chunk-XOR swizzle) --------
__global__ __launch_bounds__(256) void proj_gemm(
    const short* __restrict__ Ob, const short* __restrict__ wob,
    const float* __restrict__ bo, float* __restrict__ out)
{
    const int m0 = blockIdx.x * 64;
    const int n0 = blockIdx.y * 128;
    __shared__ short As[64 * 64];    // 8 KB
    __shared__ short Bs[128 * 64];   // 16 KB
    const int tid  = threadIdx.x;
    const int wave = tid >> 6, lane = tid & 63;
    const int quad = lane >> 4, l16 = lane & 15;
    const int wr = (wave >> 1) * 32, wc = (wave & 1) * 64;
    const int sw = l16 & 7;

    const int rS = tid >> 3;
    const int cS = (tid & 7) ^ (rS & 7);
    const short* A_src = Ob  + (size_t)(m0 + rS) * C_ + cS * 8;
    const short* B_src = wob + (size_t)(n0 + rS) * C_ + cS * 8;

    f32x4 acc[2][4] = {};

    for (int kk = 0; kk < C_; kk += 64) {
        __syncthreads();
        GLL16(A_src + kk, &As[tid * 8]);
        GLL16(A_src + (size_t)32 * C_ + kk, &As[(tid + 256) * 8]);
        #pragma unroll
        for (int it = 0; it < 4; ++it)
            GLL16(B_src + (size_t)(it * 32) * C_ + kk, &Bs[it * 2048 + tid * 8]);
        __syncthreads();
        short8 af[2][2], bf[4][2];
        #pragma unroll
        for (int mi = 0; mi < 2; ++mi) {
            int row = (wr + mi * 16 + l16) * 64;
            af[mi][0] = *(const short8*)&As[row + ((quad    ) ^ sw) * 8];
            af[mi][1] = *(const short8*)&As[row + ((quad + 4) ^ sw) * 8];
        }
        #pragma unroll
        for (int ni = 0; ni < 4; ++ni) {
            int row = (wc + ni * 16 + l16) * 64;
            bf[ni][0] = *(const short8*)&Bs[row + ((quad    ) ^ sw) * 8];
            bf[ni][1] = *(const short8*)&Bs[row + ((quad + 4) ^ sw) * 8];
        }
        #pragma unroll
        for (int k2 = 0; k2 < 2; ++k2)
        #pragma unroll
        for (int mi = 0; mi < 2; ++mi)
        #pragma unroll
        for (int ni = 0; ni < 4; ++ni)
            acc[mi][ni] = MFMA(af[mi][k2], bf[ni][k2], acc[mi][ni]);
    }

    #pragma unroll
    for (int mi = 0; mi < 2; ++mi)
    #pragma unroll
    for (int ni = 0; ni < 4; ++ni)
    #pragma unroll
    for (int r = 0; r < 4; ++r) {
        int m = m0 + wr + mi * 16 + quad * 4 + r;
        int c = n0 + wc + ni * 16 + l16;
        out[(size_t)m * C_ + c] = acc[mi][ni][r] + bo[c];
    }
}

extern "C" void kernel_launch(void* const* d_in, const int* in_sizes, int n_in,
                              void* d_out, int out_size, void* d_ws, size_t ws_size,
                              hipStream_t stream) {
    const float* x  = (const float*)d_in[0];
    const float* wq = (const float*)d_in[1];
    const float* wk = (const float*)d_in[2];
    const float* wv = (const float*)d_in[3];
    const float* wo = (const float*)d_in[4];
    const float* bo = (const float*)d_in[5];
    float* out = (float*)d_out;

    short* xb  = (short*)d_ws;        // 4M shorts
    short* Wb  = xb  + 4194304;       // 3M (wq|wk|wv)
    short* wob = Wb  + 3145728;       // 1M
    short* Qb  = wob + 1048576;       // 4M
    short* Kb  = Qb  + 4194304;       // 4M
    short* Vt  = Kb  + 4194304;       // 4M
    short* Obuf= Vt  + 4194304;       // 4M
    float* Opart = (float*)(Obuf + 4194304);  // 2 x 4.19M f32 (split partials)
    float* lpart = Opart + 2 * 4194304;       // 2 x 65536 f32

    dim3 blk(256);
    convert_kernel<<<4096, blk, 0, stream>>>(x, wq, wk, wv, wo, xb);
    qkv_gemm<<<dim3(M_ / 128, 3072 / 128), blk, 0, stream>>>(xb, Wb, Qb, Kb, Vt);
    attn_split<<<1024, blk, 0, stream>>>(Qb, Kb, Vt, Opart, lpart);
    merge_kernel<<<2048, blk, 0, stream>>>(Opart, lpart, Obuf);
    proj_gemm<<<dim3(M_ / 64, C_ / 128), blk, 0, stream>>>(Obuf, wob, bo, out);
}

// Round 8
// 186.905 us; speedup vs baseline: 1.0542x; 1.0204x over previous
//
#include <hip/hip_runtime.h>
#include <hip/hip_bf16.h>

typedef float f32x4 __attribute__((ext_vector_type(4)));
typedef short short8 __attribute__((ext_vector_type(8)));
typedef short short4v __attribute__((ext_vector_type(4)));

#define MFMA(a, b, c) __builtin_amdgcn_mfma_f32_16x16x32_bf16((a), (b), (c), 0, 0, 0)

#if __has_builtin(__builtin_amdgcn_exp2f)
#define EXP2(x) __builtin_amdgcn_exp2f(x)
#else
#define EXP2(x) exp2f(x)
#endif

#define B_  2
#define N_  2048
#define C_  1024
#define H_  16
#define HD_ 64
#define M_  (B_ * N_)   // 4096

// softmax scale (1/8) * log2(e), folded into Q at qkv epilogue
#define QSCALE 0.18033688011112042f

typedef const __attribute__((address_space(1))) void* gp_t;
typedef __attribute__((address_space(3))) void* sp_t;
#define GLL16(g, s) __builtin_amdgcn_global_load_lds((gp_t)(const void*)(g), (sp_t)(void*)(s), 16, 0, 0)

__device__ __forceinline__ short f2bf(float f) {
    union { float fv; unsigned u; } v; v.fv = f;
    unsigned r = v.u + 0x7fffu + ((v.u >> 16) & 1u);  // RNE
    return (short)(r >> 16);
}
__device__ __forceinline__ unsigned pack_rne(float a, float b) {
    return (unsigned)(unsigned short)f2bf(a) | ((unsigned)(unsigned short)f2bf(b) << 16);
}

// ---------------- fp32 -> bf16 conversion pass ----------------
__global__ __launch_bounds__(256) void convert_kernel(
    const float* __restrict__ x,  const float* __restrict__ wq,
    const float* __restrict__ wk, const float* __restrict__ wv,
    const float* __restrict__ wo, short* __restrict__ dst)
{
    size_t e = ((size_t)blockIdx.x * 256 + threadIdx.x) * 8;
    const float* src; size_t off;
    if (e < 4194304)      { src = x;  off = e; }
    else if (e < 5242880) { src = wq; off = e - 4194304; }
    else if (e < 6291456) { src = wk; off = e - 5242880; }
    else if (e < 7340032) { src = wv; off = e - 6291456; }
    else                  { src = wo; off = e - 7340032; }
    float4 a = *(const float4*)(src + off);
    float4 b = *(const float4*)(src + off + 4);
    short8 s;
    s[0] = f2bf(a.x); s[1] = f2bf(a.y); s[2] = f2bf(a.z); s[3] = f2bf(a.w);
    s[4] = f2bf(b.x); s[5] = f2bf(b.y); s[6] = f2bf(b.z); s[7] = f2bf(b.w);
    *(short8*)(dst + e) = s;
}

// ---------------- fused QKV GEMM ------------------------------------------
// R8: minimal 2-phase double-buffer (T3 recipe-box): STAGE(next) -> compute
// (cur) -> ONE __syncthreads per K-step. Old structure paid the full stage
// round-trip raw each step (barrier; STAGE; barrier-drain; compute) — R7
// counters: MfmaUtil 19.7 / VALU 21.7 / HBM 14.6% / conflicts 0 = all idle,
// latency-bound. Static buffer pairs + unroll-by-2 body keep every
// stage/compute reference compile-time distinct (no alias-forced waits).
// __syncthreads drains vmcnt AFTER compute -> next tile's loads hide under
// ~350cy of ds_read+MFMA. LDS 64 KB -> 2 blocks/CU (accepted trade).
__global__ __launch_bounds__(256, 2) void qkv_gemm(
    const short* __restrict__ xb, const short* __restrict__ Wb,
    short* __restrict__ Qb, short* __restrict__ Kb, short* __restrict__ Vt)
{
    const int m0 = blockIdx.x * 128;
    const int n0 = blockIdx.y * 128;
    __shared__ short As0[128 * 64], Bs0[128 * 64];   // 32 KB
    __shared__ short As1[128 * 64], Bs1[128 * 64];   // 32 KB
    const int tid  = threadIdx.x;
    const int wave = tid >> 6, lane = tid & 63;
    const int quad = lane >> 4, l16 = lane & 15;
    const int wr = (wave >> 1) * 64, wc = (wave & 1) * 64;
    const int sw = l16 & 7;

    const int rS = tid >> 3;
    const int cS = (tid & 7) ^ (rS & 7);
    const short* A_src = xb + (size_t)(m0 + rS) * C_ + cS * 8;
    const short* B_src = Wb + (size_t)(n0 + rS) * C_ + cS * 8;

#define QKV_STAGE(AS, BS, kk) do { \
    _Pragma("unroll") \
    for (int it = 0; it < 4; ++it) { \
        GLL16(A_src + (size_t)(it * 32) * C_ + (kk), &AS[it * 2048 + tid * 8]); \
        GLL16(B_src + (size_t)(it * 32) * C_ + (kk), &BS[it * 2048 + tid * 8]); \
    } } while (0)

#define QKV_COMPUTE(AS, BS) do { \
    short8 af[4][2], bf[4][2]; \
    _Pragma("unroll") \
    for (int mi = 0; mi < 4; ++mi) { \
        int row = (wr + mi * 16 + l16) * 64; \
        af[mi][0] = *(const short8*)&AS[row + ((quad    ) ^ sw) * 8]; \
        af[mi][1] = *(const short8*)&AS[row + ((quad + 4) ^ sw) * 8]; \
    } \
    _Pragma("unroll") \
    for (int ni = 0; ni < 4; ++ni) { \
        int row = (wc + ni * 16 + l16) * 64; \
        bf[ni][0] = *(const short8*)&BS[row + ((quad    ) ^ sw) * 8]; \
        bf[ni][1] = *(const short8*)&BS[row + ((quad + 4) ^ sw) * 8]; \
    } \
    __builtin_amdgcn_s_setprio(1); \
    _Pragma("unroll") \
    for (int k2 = 0; k2 < 2; ++k2) \
    _Pragma("unroll") \
    for (int mi = 0; mi < 4; ++mi) \
    _Pragma("unroll") \
    for (int ni = 0; ni < 4; ++ni) \
        acc[mi][ni] = MFMA(af[mi][k2], bf[ni][k2], acc[mi][ni]); \
    __builtin_amdgcn_s_setprio(0); } while (0)

    f32x4 acc[4][4] = {};

    QKV_STAGE(As0, Bs0, 0);
    __syncthreads();
    for (int t2 = 0; t2 < 8; ++t2) {
        const int kk1 = t2 * 128 + 64;
        QKV_STAGE(As1, Bs1, kk1);
        QKV_COMPUTE(As0, Bs0);
        __syncthreads();
        if (t2 < 7) QKV_STAGE(As0, Bs0, kk1 + 64);
        QKV_COMPUTE(As1, Bs1);
        __syncthreads();
    }
#undef QKV_STAGE
#undef QKV_COMPUTE

    const int which = n0 >> 10;        // block-uniform: 0=Q 1=K 2=V
    const int nb = n0 & 1023;
    #pragma unroll
    for (int mi = 0; mi < 4; ++mi)
    #pragma unroll
    for (int ni = 0; ni < 4; ++ni)
    #pragma unroll
    for (int r = 0; r < 4; ++r) {
        int m  = m0 + wr + mi * 16 + quad * 4 + r;
        int cc = nb + wc + ni * 16 + l16;
        float av = acc[mi][ni][r];
        if (which == 0) av *= QSCALE;
        short bv = f2bf(av);
        int bb = m >> 11, ns = m & (N_ - 1);
        int h = cc >> 6, d = cc & 63;
        size_t bh = (size_t)(bb * H_ + h);
        if (which == 0)      Qb[(bh * N_ + ns) * HD_ + d] = bv;
        else if (which == 1) Kb[(bh * N_ + ns) * HD_ + d] = bv;
        else                 Vt[(bh * HD_ + d) * N_ + ns] = bv;  // V transposed
    }
}

// ---------------- Flash attention, split-j x2, 2-strip (R7, frozen) --------
__global__ __launch_bounds__(256, 4) void attn_split(
    const short* __restrict__ Qb, const short* __restrict__ Kb,
    const short* __restrict__ Vt, float* __restrict__ Opart,
    float* __restrict__ lpart)
{
    // 1024 blocks; XCD-chunk (1024 % 8 == 0): 128 per XCD -> 4 bh per XCD.
    const int bid = blockIdx.x;
    const int swz = (bid & 7) * 128 + (bid >> 3);
    const int bh = swz >> 5;                 // 32
    const int i0 = ((swz >> 1) & 15) * 128;  // 16 i-tiles of 128 rows
    const int sp = swz & 1;                  // j-split: sp*1024 ..
    __shared__ short Ks[2][64 * 64];    // 16 KB
    __shared__ short Vs[2][64 * 64];    // 16 KB, Vs[d][j]
    const int tid  = threadIdx.x;
    const int wave = tid >> 6, lane = tid & 63;
    const int quad = lane >> 4, l16 = lane & 15;
    const int sw = l16 & 7;             // frag-read swizzle key (row&7 == l16&7)

    const short* Qg = Qb + ((size_t)bh * N_ + i0) * HD_;
    const short* Kg = Kb + (size_t)bh * N_ * HD_;
    const short* Vg = Vt + (size_t)bh * HD_ * N_;

    const int row0 = tid >> 3,  c0 = (tid & 7) ^ (row0 & 7);
    const int row1 = row0 + 32, c1 = (tid & 7) ^ (row1 & 7);
    const short* KgA0 = Kg + (sp * 1024 + row0) * HD_ + c0 * 8;
    const short* KgA1 = Kg + (sp * 1024 + row1) * HD_ + c1 * 8;
    const short* VgA0 = Vg + (size_t)row0 * N_ + sp * 1024 + c0 * 8;
    const short* VgA1 = Vg + (size_t)row1 * N_ + sp * 1024 + c1 * 8;

    // Q fragments: global -> reg (read once; no LDS round-trip); 2 strips.
    short8 qf[2][2];
    #pragma unroll
    for (int s = 0; s < 2; ++s) {
        const short* qrow = Qg + (wave * 32 + s * 16 + l16) * HD_;
        qf[s][0] = *(const short8*)(qrow + quad * 8);
        qf[s][1] = *(const short8*)(qrow + quad * 8 + 32);
    }

    GLL16(KgA0, &Ks[0][tid * 8]);
    GLL16(KgA1, &Ks[0][(tid + 256) * 8]);
    GLL16(VgA0, &Vs[0][tid * 8]);
    GLL16(VgA1, &Vs[0][(tid + 256) * 8]);
    __syncthreads();

    f32x4 o[2][4] = {};
    float lrow[2] = {0.f, 0.f};

    for (int jt = 0; jt < 16; ++jt) {
        const int cur = jt & 1;
        if (jt + 1 < 16) {
            int j1 = (jt + 1) * 64;
            GLL16(KgA0 + (size_t)j1 * HD_, &Ks[cur ^ 1][tid * 8]);
            GLL16(KgA1 + (size_t)j1 * HD_, &Ks[cur ^ 1][(tid + 256) * 8]);
            GLL16(VgA0 + j1, &Vs[cur ^ 1][tid * 8]);
            GLL16(VgA1 + j1, &Vs[cur ^ 1][(tid + 256) * 8]);
        }
        const short* Kc = Ks[cur];
        const short* Vc = Vs[cur];

        #pragma unroll
        for (int half = 0; half < 2; ++half) {
            // S^T for ni = 2*half, 2*half+1; K frags read once, used by both
            // strips. P stays in registers as the permuted PV B-fragment.
            unsigned pq[2][4];
            #pragma unroll
            for (int nio = 0; nio < 2; ++nio) {
                int ni = half * 2 + nio;
                int krow = (ni * 16 + l16) * 64;
                short8 kf0 = *(const short8*)&Kc[krow + ((quad ^ sw) * 8)];
                short8 kf1 = *(const short8*)&Kc[krow + (((quad + 4) ^ sw) * 8)];
                #pragma unroll
                for (int s = 0; s < 2; ++s) {
                    f32x4 st = {0.f, 0.f, 0.f, 0.f};
                    __builtin_amdgcn_s_setprio(1);
                    st = MFMA(kf0, qf[s][0], st);
                    st = MFMA(kf1, qf[s][1], st);   // S^T[j=16ni+4q+r][i=strip+l16]
                    __builtin_amdgcn_s_setprio(0);
                    union { float f; unsigned u; } e0, e1, e2, e3;
                    e0.f = EXP2(st[0]); e1.f = EXP2(st[1]);
                    e2.f = EXP2(st[2]); e3.f = EXP2(st[3]);
                    lrow[s] += (e0.f + e1.f) + (e2.f + e3.f);
                    pq[s][nio * 2]     = __builtin_amdgcn_perm(e1.u, e0.u, 0x07060302u);
                    pq[s][nio * 2 + 1] = __builtin_amdgcn_perm(e3.u, e2.u, 0x07060302u);
                }
            }
            // PV: V frags read once per di, shared across strips.
            #pragma unroll
            for (int di = 0; di < 4; ++di) {
                int vrow = (di * 16 + l16) * 64;
                int ch1 = (half * 4 +     (quad >> 1)) ^ sw;
                int ch2 = (half * 4 + 2 + (quad >> 1)) ^ sw;
                union { struct { short4v lo, hi; } p; short8 v; } va;
                va.p.lo = *(const short4v*)&Vc[vrow + ch1 * 8 + (quad & 1) * 4];
                va.p.hi = *(const short4v*)&Vc[vrow + ch2 * 8 + (quad & 1) * 4];
                __builtin_amdgcn_s_setprio(1);
                #pragma unroll
                for (int s = 0; s < 2; ++s) {
                    union { unsigned u[4]; short8 v; } pb;
                    pb.u[0] = pq[s][0]; pb.u[1] = pq[s][1];
                    pb.u[2] = pq[s][2]; pb.u[3] = pq[s][3];
                    o[s][di] = MFMA(va.v, pb.v, o[s][di]);
                }
                __builtin_amdgcn_s_setprio(0);
            }
        }
        __syncthreads();
    }

    #pragma unroll
    for (int s = 0; s < 2; ++s) {
        float l = lrow[s];
        l += __shfl_xor(l, 16, 64);
        l += __shfl_xor(l, 32, 64);
        int ig = i0 + wave * 32 + s * 16 + l16;
        float* obase = Opart + ((size_t)(sp * 32 + bh) * N_ + ig) * HD_;
        #pragma unroll
        for (int di = 0; di < 4; ++di)   // d = di*16 + quad*4 + r, unnormalized
            *(f32x4*)(obase + di * 16 + quad * 4) = o[s][di];
        if (quad == 0) lpart[sp * 65536 + bh * N_ + ig] = l;
    }
}

// merge: O = (O0 + O1) / (l0 + l1), scatter to head-interleaved bf16 layout
__global__ __launch_bounds__(256) void merge_kernel(
    const float* __restrict__ Opart, const float* __restrict__ lpart,
    short* __restrict__ Ob)
{
    int e8 = (blockIdx.x * 256 + threadIdx.x) * 8;   // [bh][ig][d] linear
    int bh = e8 >> 17;
    int rem = e8 & 131071;
    int ig = rem >> 6, d = rem & 63;
    f32x4 a0 = *(const f32x4*)(Opart + e8);
    f32x4 a1 = *(const f32x4*)(Opart + e8 + 4);
    f32x4 b0 = *(const f32x4*)(Opart + 4194304 + e8);
    f32x4 b1 = *(const f32x4*)(Opart + 4194304 + e8 + 4);
    float inv = 1.f / (lpart[bh * N_ + ig] + lpart[65536 + bh * N_ + ig]);
    short8 s;
    s[0] = f2bf((a0[0] + b0[0]) * inv); s[1] = f2bf((a0[1] + b0[1]) * inv);
    s[2] = f2bf((a0[2] + b0[2]) * inv); s[3] = f2bf((a0[3] + b0[3]) * inv);
    s[4] = f2bf((a1[0] + b1[0]) * inv); s[5] = f2bf((a1[1] + b1[1]) * inv);
    s[6] = f2bf((a1[2] + b1[2]) * inv); s[7] = f2bf((a1[3] + b1[3]) * inv);
    int b = bh >> 4, h = bh & (H_ - 1);
    *(short8*)&Ob[((size_t)(b * N_ + ig)) * C_ + h * HD_ + d] = s;
}

// ---------------- Output projection (R4: BK=64 + chunk-XOR swizzle) --------
__global__ __launch_bounds__(256) void proj_gemm(
    const short* __restrict__ Ob, const short* __restrict__ wob,
    const float* __restrict__ bo, float* __restrict__ out)
{
    const int m0 = blockIdx.x * 64;
    const int n0 = blockIdx.y * 128;
    __shared__ short As[64 * 64];    // 8 KB
    __shared__ short Bs[128 * 64];   // 16 KB
    const int tid  = threadIdx.x;
    const int wave = tid >> 6, lane = tid & 63;
    const int quad = lane >> 4, l16 = lane & 15;
    const int wr = (wave >> 1) * 32, wc = (wave & 1) * 64;
    const int sw = l16 & 7;

    const int rS = tid >> 3;
    const int cS = (tid & 7) ^ (rS & 7);
    const short* A_src = Ob  + (size_t)(m0 + rS) * C_ + cS * 8;
    const short* B_src = wob + (size_t)(n0 + rS) * C_ + cS * 8;

    f32x4 acc[2][4] = {};

    for (int kk = 0; kk < C_; kk += 64) {
        __syncthreads();
        GLL16(A_src + kk, &As[tid * 8]);
        GLL16(A_src + (size_t)32 * C_ + kk, &As[(tid + 256) * 8]);
        #pragma unroll
        for (int it = 0; it < 4; ++it)
            GLL16(B_src + (size_t)(it * 32) * C_ + kk, &Bs[it * 2048 + tid * 8]);
        __syncthreads();
        short8 af[2][2], bf[4][2];
        #pragma unroll
        for (int mi = 0; mi < 2; ++mi) {
            int row = (wr + mi * 16 + l16) * 64;
            af[mi][0] = *(const short8*)&As[row + ((quad    ) ^ sw) * 8];
            af[mi][1] = *(const short8*)&As[row + ((quad + 4) ^ sw) * 8];
        }
        #pragma unroll
        for (int ni = 0; ni < 4; ++ni) {
            int row = (wc + ni * 16 + l16) * 64;
            bf[ni][0] = *(const short8*)&Bs[row + ((quad    ) ^ sw) * 8];
            bf[ni][1] = *(const short8*)&Bs[row + ((quad + 4) ^ sw) * 8];
        }
        #pragma unroll
        for (int k2 = 0; k2 < 2; ++k2)
        #pragma unroll
        for (int mi = 0; mi < 2; ++mi)
        #pragma unroll
        for (int ni = 0; ni < 4; ++ni)
            acc[mi][ni] = MFMA(af[mi][k2], bf[ni][k2], acc[mi][ni]);
    }

    #pragma unroll
    for (int mi = 0; mi < 2; ++mi)
    #pragma unroll
    for (int ni = 0; ni < 4; ++ni)
    #pragma unroll
    for (int r = 0; r < 4; ++r) {
        int m = m0 + wr + mi * 16 + quad * 4 + r;
        int c = n0 + wc + ni * 16 + l16;
        out[(size_t)m * C_ + c] = acc[mi][ni][r] + bo[c];
    }
}

extern "C" void kernel_launch(void* const* d_in, const int* in_sizes, int n_in,
                              void* d_out, int out_size, void* d_ws, size_t ws_size,
                              hipStream_t stream) {
    const float* x  = (const float*)d_in[0];
    const float* wq = (const float*)d_in[1];
    const float* wk = (const float*)d_in[2];
    const float* wv = (const float*)d_in[3];
    const float* wo = (const float*)d_in[4];
    const float* bo = (const float*)d_in[5];
    float* out = (float*)d_out;

    short* xb  = (short*)d_ws;        // 4M shorts
    short* Wb  = xb  + 4194304;       // 3M (wq|wk|wv)
    short* wob = Wb  + 3145728;       // 1M
    short* Qb  = wob + 1048576;       // 4M
    short* Kb  = Qb  + 4194304;       // 4M
    short* Vt  = Kb  + 4194304;       // 4M
    short* Obuf= Vt  + 4194304;       // 4M
    float* Opart = (float*)(Obuf + 4194304);  // 2 x 4.19M f32 (split partials)
    float* lpart = Opart + 2 * 4194304;       // 2 x 65536 f32

    dim3 blk(256);
    convert_kernel<<<4096, blk, 0, stream>>>(x, wq, wk, wv, wo, xb);
    qkv_gemm<<<dim3(M_ / 128, 3072 / 128), blk, 0, stream>>>(xb, Wb, Qb, Kb, Vt);
    attn_split<<<1024, blk, 0, stream>>>(Qb, Kb, Vt, Opart, lpart);
    merge_kernel<<<2048, blk, 0, stream>>>(Opart, lpart, Obuf);
    proj_gemm<<<dim3(M_ / 64, C_ / 128), blk, 0, stream>>>(Obuf, wob, bo, out);
}

// Round 9
// 177.611 us; speedup vs baseline: 1.1093x; 1.0523x over previous
//
#include <hip/hip_runtime.h>
#include <hip/hip_bf16.h>

typedef float f32x4 __attribute__((ext_vector_type(4)));
typedef short short8 __attribute__((ext_vector_type(8)));
typedef short short4v __attribute__((ext_vector_type(4)));

#define MFMA(a, b, c) __builtin_amdgcn_mfma_f32_16x16x32_bf16((a), (b), (c), 0, 0, 0)

#if __has_builtin(__builtin_amdgcn_exp2f)
#define EXP2(x) __builtin_amdgcn_exp2f(x)
#else
#define EXP2(x) exp2f(x)
#endif

#define B_  2
#define N_  2048
#define C_  1024
#define H_  16
#define HD_ 64
#define M_  (B_ * N_)   // 4096

// softmax scale (1/8) * log2(e), folded into Q at qkv epilogue
#define QSCALE 0.18033688011112042f

typedef const __attribute__((address_space(1))) void* gp_t;
typedef __attribute__((address_space(3))) void* sp_t;
#define GLL16(g, s) __builtin_amdgcn_global_load_lds((gp_t)(const void*)(g), (sp_t)(void*)(s), 16, 0, 0)

__device__ __forceinline__ short f2bf(float f) {
    union { float fv; unsigned u; } v; v.fv = f;
    unsigned r = v.u + 0x7fffu + ((v.u >> 16) & 1u);  // RNE
    return (short)(r >> 16);
}
__device__ __forceinline__ unsigned pack_rne(float a, float b) {
    return (unsigned)(unsigned short)f2bf(a) | ((unsigned)(unsigned short)f2bf(b) << 16);
}

// ---------------- fp32 -> bf16 conversion pass ----------------
__global__ __launch_bounds__(256) void convert_kernel(
    const float* __restrict__ x,  const float* __restrict__ wq,
    const float* __restrict__ wk, const float* __restrict__ wv,
    const float* __restrict__ wo, short* __restrict__ dst)
{
    size_t e = ((size_t)blockIdx.x * 256 + threadIdx.x) * 8;
    const float* src; size_t off;
    if (e < 4194304)      { src = x;  off = e; }
    else if (e < 5242880) { src = wq; off = e - 4194304; }
    else if (e < 6291456) { src = wk; off = e - 5242880; }
    else if (e < 7340032) { src = wv; off = e - 6291456; }
    else                  { src = wo; off = e - 7340032; }
    float4 a = *(const float4*)(src + off);
    float4 b = *(const float4*)(src + off + 4);
    short8 s;
    s[0] = f2bf(a.x); s[1] = f2bf(a.y); s[2] = f2bf(a.z); s[3] = f2bf(a.w);
    s[4] = f2bf(b.x); s[5] = f2bf(b.y); s[6] = f2bf(b.z); s[7] = f2bf(b.w);
    *(short8*)(dst + e) = s;
}

// ---------------- fused QKV GEMM (R8: 2-phase dbuf, frozen) ----------------
__global__ __launch_bounds__(256, 2) void qkv_gemm(
    const short* __restrict__ xb, const short* __restrict__ Wb,
    short* __restrict__ Qb, short* __restrict__ Kb, short* __restrict__ Vt)
{
    const int m0 = blockIdx.x * 128;
    const int n0 = blockIdx.y * 128;
    __shared__ short As0[128 * 64], Bs0[128 * 64];   // 32 KB
    __shared__ short As1[128 * 64], Bs1[128 * 64];   // 32 KB
    const int tid  = threadIdx.x;
    const int wave = tid >> 6, lane = tid & 63;
    const int quad = lane >> 4, l16 = lane & 15;
    const int wr = (wave >> 1) * 64, wc = (wave & 1) * 64;
    const int sw = l16 & 7;

    const int rS = tid >> 3;
    const int cS = (tid & 7) ^ (rS & 7);
    const short* A_src = xb + (size_t)(m0 + rS) * C_ + cS * 8;
    const short* B_src = Wb + (size_t)(n0 + rS) * C_ + cS * 8;

#define QKV_STAGE(AS, BS, kk) do { \
    _Pragma("unroll") \
    for (int it = 0; it < 4; ++it) { \
        GLL16(A_src + (size_t)(it * 32) * C_ + (kk), &AS[it * 2048 + tid * 8]); \
        GLL16(B_src + (size_t)(it * 32) * C_ + (kk), &BS[it * 2048 + tid * 8]); \
    } } while (0)

#define QKV_COMPUTE(AS, BS) do { \
    short8 af[4][2], bf[4][2]; \
    _Pragma("unroll") \
    for (int mi = 0; mi < 4; ++mi) { \
        int row = (wr + mi * 16 + l16) * 64; \
        af[mi][0] = *(const short8*)&AS[row + ((quad    ) ^ sw) * 8]; \
        af[mi][1] = *(const short8*)&AS[row + ((quad + 4) ^ sw) * 8]; \
    } \
    _Pragma("unroll") \
    for (int ni = 0; ni < 4; ++ni) { \
        int row = (wc + ni * 16 + l16) * 64; \
        bf[ni][0] = *(const short8*)&BS[row + ((quad    ) ^ sw) * 8]; \
        bf[ni][1] = *(const short8*)&BS[row + ((quad + 4) ^ sw) * 8]; \
    } \
    __builtin_amdgcn_s_setprio(1); \
    _Pragma("unroll") \
    for (int k2 = 0; k2 < 2; ++k2) \
    _Pragma("unroll") \
    for (int mi = 0; mi < 4; ++mi) \
    _Pragma("unroll") \
    for (int ni = 0; ni < 4; ++ni) \
        acc[mi][ni] = MFMA(af[mi][k2], bf[ni][k2], acc[mi][ni]); \
    __builtin_amdgcn_s_setprio(0); } while (0)

    f32x4 acc[4][4] = {};

    QKV_STAGE(As0, Bs0, 0);
    __syncthreads();
    for (int t2 = 0; t2 < 8; ++t2) {
        const int kk1 = t2 * 128 + 64;
        QKV_STAGE(As1, Bs1, kk1);
        QKV_COMPUTE(As0, Bs0);
        __syncthreads();
        if (t2 < 7) QKV_STAGE(As0, Bs0, kk1 + 64);
        QKV_COMPUTE(As1, Bs1);
        __syncthreads();
    }
#undef QKV_STAGE
#undef QKV_COMPUTE

    const int which = n0 >> 10;        // block-uniform: 0=Q 1=K 2=V
    const int nb = n0 & 1023;
    #pragma unroll
    for (int mi = 0; mi < 4; ++mi)
    #pragma unroll
    for (int ni = 0; ni < 4; ++ni)
    #pragma unroll
    for (int r = 0; r < 4; ++r) {
        int m  = m0 + wr + mi * 16 + quad * 4 + r;
        int cc = nb + wc + ni * 16 + l16;
        float av = acc[mi][ni][r];
        if (which == 0) av *= QSCALE;
        short bv = f2bf(av);
        int bb = m >> 11, ns = m & (N_ - 1);
        int h = cc >> 6, d = cc & 63;
        size_t bh = (size_t)(bb * H_ + h);
        if (which == 0)      Qb[(bh * N_ + ns) * HD_ + d] = bv;
        else if (which == 1) Kb[(bh * N_ + ns) * HD_ + d] = bv;
        else                 Vt[(bh * HD_ + d) * N_ + ns] = bv;  // V transposed
    }
}

// ---------------- Flash attention, split-j x2, 2-strip (R7, frozen) --------
__global__ __launch_bounds__(256, 4) void attn_split(
    const short* __restrict__ Qb, const short* __restrict__ Kb,
    const short* __restrict__ Vt, float* __restrict__ Opart,
    float* __restrict__ lpart)
{
    // 1024 blocks; XCD-chunk (1024 % 8 == 0): 128 per XCD -> 4 bh per XCD.
    const int bid = blockIdx.x;
    const int swz = (bid & 7) * 128 + (bid >> 3);
    const int bh = swz >> 5;                 // 32
    const int i0 = ((swz >> 1) & 15) * 128;  // 16 i-tiles of 128 rows
    const int sp = swz & 1;                  // j-split: sp*1024 ..
    __shared__ short Ks[2][64 * 64];    // 16 KB
    __shared__ short Vs[2][64 * 64];    // 16 KB, Vs[d][j]
    const int tid  = threadIdx.x;
    const int wave = tid >> 6, lane = tid & 63;
    const int quad = lane >> 4, l16 = lane & 15;
    const int sw = l16 & 7;             // frag-read swizzle key (row&7 == l16&7)

    const short* Qg = Qb + ((size_t)bh * N_ + i0) * HD_;
    const short* Kg = Kb + (size_t)bh * N_ * HD_;
    const short* Vg = Vt + (size_t)bh * HD_ * N_;

    const int row0 = tid >> 3,  c0 = (tid & 7) ^ (row0 & 7);
    const int row1 = row0 + 32, c1 = (tid & 7) ^ (row1 & 7);
    const short* KgA0 = Kg + (sp * 1024 + row0) * HD_ + c0 * 8;
    const short* KgA1 = Kg + (sp * 1024 + row1) * HD_ + c1 * 8;
    const short* VgA0 = Vg + (size_t)row0 * N_ + sp * 1024 + c0 * 8;
    const short* VgA1 = Vg + (size_t)row1 * N_ + sp * 1024 + c1 * 8;

    // Q fragments: global -> reg (read once; no LDS round-trip); 2 strips.
    short8 qf[2][2];
    #pragma unroll
    for (int s = 0; s < 2; ++s) {
        const short* qrow = Qg + (wave * 32 + s * 16 + l16) * HD_;
        qf[s][0] = *(const short8*)(qrow + quad * 8);
        qf[s][1] = *(const short8*)(qrow + quad * 8 + 32);
    }

    GLL16(KgA0, &Ks[0][tid * 8]);
    GLL16(KgA1, &Ks[0][(tid + 256) * 8]);
    GLL16(VgA0, &Vs[0][tid * 8]);
    GLL16(VgA1, &Vs[0][(tid + 256) * 8]);
    __syncthreads();

    f32x4 o[2][4] = {};
    float lrow[2] = {0.f, 0.f};

    for (int jt = 0; jt < 16; ++jt) {
        const int cur = jt & 1;
        if (jt + 1 < 16) {
            int j1 = (jt + 1) * 64;
            GLL16(KgA0 + (size_t)j1 * HD_, &Ks[cur ^ 1][tid * 8]);
            GLL16(KgA1 + (size_t)j1 * HD_, &Ks[cur ^ 1][(tid + 256) * 8]);
            GLL16(VgA0 + j1, &Vs[cur ^ 1][tid * 8]);
            GLL16(VgA1 + j1, &Vs[cur ^ 1][(tid + 256) * 8]);
        }
        const short* Kc = Ks[cur];
        const short* Vc = Vs[cur];

        #pragma unroll
        for (int half = 0; half < 2; ++half) {
            // S^T for ni = 2*half, 2*half+1; K frags read once, used by both
            // strips. P stays in registers as the permuted PV B-fragment.
            unsigned pq[2][4];
            #pragma unroll
            for (int nio = 0; nio < 2; ++nio) {
                int ni = half * 2 + nio;
                int krow = (ni * 16 + l16) * 64;
                short8 kf0 = *(const short8*)&Kc[krow + ((quad ^ sw) * 8)];
                short8 kf1 = *(const short8*)&Kc[krow + (((quad + 4) ^ sw) * 8)];
                #pragma unroll
                for (int s = 0; s < 2; ++s) {
                    f32x4 st = {0.f, 0.f, 0.f, 0.f};
                    __builtin_amdgcn_s_setprio(1);
                    st = MFMA(kf0, qf[s][0], st);
                    st = MFMA(kf1, qf[s][1], st);   // S^T[j=16ni+4q+r][i=strip+l16]
                    __builtin_amdgcn_s_setprio(0);
                    union { float f; unsigned u; } e0, e1, e2, e3;
                    e0.f = EXP2(st[0]); e1.f = EXP2(st[1]);
                    e2.f = EXP2(st[2]); e3.f = EXP2(st[3]);
                    lrow[s] += (e0.f + e1.f) + (e2.f + e3.f);
                    pq[s][nio * 2]     = __builtin_amdgcn_perm(e1.u, e0.u, 0x07060302u);
                    pq[s][nio * 2 + 1] = __builtin_amdgcn_perm(e3.u, e2.u, 0x07060302u);
                }
            }
            // PV: V frags read once per di, shared across strips.
            #pragma unroll
            for (int di = 0; di < 4; ++di) {
                int vrow = (di * 16 + l16) * 64;
                int ch1 = (half * 4 +     (quad >> 1)) ^ sw;
                int ch2 = (half * 4 + 2 + (quad >> 1)) ^ sw;
                union { struct { short4v lo, hi; } p; short8 v; } va;
                va.p.lo = *(const short4v*)&Vc[vrow + ch1 * 8 + (quad & 1) * 4];
                va.p.hi = *(const short4v*)&Vc[vrow + ch2 * 8 + (quad & 1) * 4];
                __builtin_amdgcn_s_setprio(1);
                #pragma unroll
                for (int s = 0; s < 2; ++s) {
                    union { unsigned u[4]; short8 v; } pb;
                    pb.u[0] = pq[s][0]; pb.u[1] = pq[s][1];
                    pb.u[2] = pq[s][2]; pb.u[3] = pq[s][3];
                    o[s][di] = MFMA(va.v, pb.v, o[s][di]);
                }
                __builtin_amdgcn_s_setprio(0);
            }
        }
        __syncthreads();
    }

    #pragma unroll
    for (int s = 0; s < 2; ++s) {
        float l = lrow[s];
        l += __shfl_xor(l, 16, 64);
        l += __shfl_xor(l, 32, 64);
        int ig = i0 + wave * 32 + s * 16 + l16;
        float* obase = Opart + ((size_t)(sp * 32 + bh) * N_ + ig) * HD_;
        #pragma unroll
        for (int di = 0; di < 4; ++di)   // d = di*16 + quad*4 + r, unnormalized
            *(f32x4*)(obase + di * 16 + quad * 4) = o[s][di];
        if (quad == 0) lpart[sp * 65536 + bh * N_ + ig] = l;
    }
}

// merge: O = (O0 + O1) / (l0 + l1), scatter to head-interleaved bf16 layout
__global__ __launch_bounds__(256) void merge_kernel(
    const float* __restrict__ Opart, const float* __restrict__ lpart,
    short* __restrict__ Ob)
{
    int e8 = (blockIdx.x * 256 + threadIdx.x) * 8;   // [bh][ig][d] linear
    int bh = e8 >> 17;
    int rem = e8 & 131071;
    int ig = rem >> 6, d = rem & 63;
    f32x4 a0 = *(const f32x4*)(Opart + e8);
    f32x4 a1 = *(const f32x4*)(Opart + e8 + 4);
    f32x4 b0 = *(const f32x4*)(Opart + 4194304 + e8);
    f32x4 b1 = *(const f32x4*)(Opart + 4194304 + e8 + 4);
    float inv = 1.f / (lpart[bh * N_ + ig] + lpart[65536 + bh * N_ + ig]);
    short8 s;
    s[0] = f2bf((a0[0] + b0[0]) * inv); s[1] = f2bf((a0[1] + b0[1]) * inv);
    s[2] = f2bf((a0[2] + b0[2]) * inv); s[3] = f2bf((a0[3] + b0[3]) * inv);
    s[4] = f2bf((a1[0] + b1[0]) * inv); s[5] = f2bf((a1[1] + b1[1]) * inv);
    s[6] = f2bf((a1[2] + b1[2]) * inv); s[7] = f2bf((a1[3] + b1[3]) * inv);
    int b = bh >> 4, h = bh & (H_ - 1);
    *(short8*)&Ob[((size_t)(b * N_ + ig)) * C_ + h * HD_ + d] = s;
}

// ---------------- Output projection ----------------------------------------
// R9: R8's 2-phase dbuf transform applied verbatim (STAGE(next) ->
// COMPUTE(cur) -> one __syncthreads). proj was the last single-buffered
// GEMM (the R7-qkv "all pipes idle" signature class). LDS 24 -> 48 KB
// (3 blocks/CU fit; grid gives 2).
__global__ __launch_bounds__(256, 2) void proj_gemm(
    const short* __restrict__ Ob, const short* __restrict__ wob,
    const float* __restrict__ bo, float* __restrict__ out)
{
    const int m0 = blockIdx.x * 64;
    const int n0 = blockIdx.y * 128;
    __shared__ short As0[64 * 64], Bs0[128 * 64];    // 24 KB
    __shared__ short As1[64 * 64], Bs1[128 * 64];    // 24 KB
    const int tid  = threadIdx.x;
    const int wave = tid >> 6, lane = tid & 63;
    const int quad = lane >> 4, l16 = lane & 15;
    const int wr = (wave >> 1) * 32, wc = (wave & 1) * 64;
    const int sw = l16 & 7;

    const int rS = tid >> 3;
    const int cS = (tid & 7) ^ (rS & 7);
    const short* A_src = Ob  + (size_t)(m0 + rS) * C_ + cS * 8;
    const short* B_src = wob + (size_t)(n0 + rS) * C_ + cS * 8;

#define PRJ_STAGE(AS, BS, kk) do { \
    GLL16(A_src + (kk), &AS[tid * 8]); \
    GLL16(A_src + (size_t)32 * C_ + (kk), &AS[(tid + 256) * 8]); \
    _Pragma("unroll") \
    for (int it = 0; it < 4; ++it) \
        GLL16(B_src + (size_t)(it * 32) * C_ + (kk), &BS[it * 2048 + tid * 8]); \
    } while (0)

#define PRJ_COMPUTE(AS, BS) do { \
    short8 af[2][2], bf[4][2]; \
    _Pragma("unroll") \
    for (int mi = 0; mi < 2; ++mi) { \
        int row = (wr + mi * 16 + l16) * 64; \
        af[mi][0] = *(const short8*)&AS[row + ((quad    ) ^ sw) * 8]; \
        af[mi][1] = *(const short8*)&AS[row + ((quad + 4) ^ sw) * 8]; \
    } \
    _Pragma("unroll") \
    for (int ni = 0; ni < 4; ++ni) { \
        int row = (wc + ni * 16 + l16) * 64; \
        bf[ni][0] = *(const short8*)&BS[row + ((quad    ) ^ sw) * 8]; \
        bf[ni][1] = *(const short8*)&BS[row + ((quad + 4) ^ sw) * 8]; \
    } \
    __builtin_amdgcn_s_setprio(1); \
    _Pragma("unroll") \
    for (int k2 = 0; k2 < 2; ++k2) \
    _Pragma("unroll") \
    for (int mi = 0; mi < 2; ++mi) \
    _Pragma("unroll") \
    for (int ni = 0; ni < 4; ++ni) \
        acc[mi][ni] = MFMA(af[mi][k2], bf[ni][k2], acc[mi][ni]); \
    __builtin_amdgcn_s_setprio(0); } while (0)

    f32x4 acc[2][4] = {};

    PRJ_STAGE(As0, Bs0, 0);
    __syncthreads();
    for (int t2 = 0; t2 < 8; ++t2) {
        const int kk1 = t2 * 128 + 64;
        PRJ_STAGE(As1, Bs1, kk1);
        PRJ_COMPUTE(As0, Bs0);
        __syncthreads();
        if (t2 < 7) PRJ_STAGE(As0, Bs0, kk1 + 64);
        PRJ_COMPUTE(As1, Bs1);
        __syncthreads();
    }
#undef PRJ_STAGE
#undef PRJ_COMPUTE

    #pragma unroll
    for (int mi = 0; mi < 2; ++mi)
    #pragma unroll
    for (int ni = 0; ni < 4; ++ni)
    #pragma unroll
    for (int r = 0; r < 4; ++r) {
        int m = m0 + wr + mi * 16 + quad * 4 + r;
        int c = n0 + wc + ni * 16 + l16;
        out[(size_t)m * C_ + c] = acc[mi][ni][r] + bo[c];
    }
}

extern "C" void kernel_launch(void* const* d_in, const int* in_sizes, int n_in,
                              void* d_out, int out_size, void* d_ws, size_t ws_size,
                              hipStream_t stream) {
    const float* x  = (const float*)d_in[0];
    const float* wq = (const float*)d_in[1];
    const float* wk = (const float*)d_in[2];
    const float* wv = (const float*)d_in[3];
    const float* wo = (const float*)d_in[4];
    const float* bo = (const float*)d_in[5];
    float* out = (float*)d_out;

    short* xb  = (short*)d_ws;        // 4M shorts
    short* Wb  = xb  + 4194304;       // 3M (wq|wk|wv)
    short* wob = Wb  + 3145728;       // 1M
    short* Qb  = wob + 1048576;       // 4M
    short* Kb  = Qb  + 4194304;       // 4M
    short* Vt  = Kb  + 4194304;       // 4M
    short* Obuf= Vt  + 4194304;       // 4M
    float* Opart = (float*)(Obuf + 4194304);  // 2 x 4.19M f32 (split partials)
    float* lpart = Opart + 2 * 4194304;       // 2 x 65536 f32

    dim3 blk(256);
    convert_kernel<<<4096, blk, 0, stream>>>(x, wq, wk, wv, wo, xb);
    qkv_gemm<<<dim3(M_ / 128, 3072 / 128), blk, 0, stream>>>(xb, Wb, Qb, Kb, Vt);
    attn_split<<<1024, blk, 0, stream>>>(Qb, Kb, Vt, Opart, lpart);
    merge_kernel<<<2048, blk, 0, stream>>>(Opart, lpart, Obuf);
    proj_gemm<<<dim3(M_ / 64, C_ / 128), blk, 0, stream>>>(Obuf, wob, bo, out);
}